// Round 9
// baseline (375.786 us; speedup 1.0000x reference)
//
#include <hip/hip_runtime.h>
#include <hip/hip_bf16.h>

#define N_DEC  24
#define IN_DIM 768
#define HID    128
#define ODIM   99136
#define BATCH  64
#define OTILE  256
#define NXBLK  ((ODIM + OTILE - 1) / OTILE)   // 388 (last block: 64 valid cols)

typedef __attribute__((ext_vector_type(8))) short bf16x8;
typedef __attribute__((ext_vector_type(4))) float f32x4;

static __device__ __forceinline__ short f2bf_bits(float f) {
    union { __hip_bfloat16 b; short s; } u;
    u.b = __float2bfloat16(f);
    return u.s;
}

static __device__ __forceinline__ void gload_lds16(const float* src, float* dst) {
    __builtin_amdgcn_global_load_lds(
        (const __attribute__((address_space(1))) void*)src,
        (__attribute__((address_space(3))) void*)dst, 16, 0, 0);
}

// ---------------- Kernel A ----------------
// h stored bf16 in MFMA-A-fragment swizzled order (validated R3-R8):
// per n, chunk c = (ks*4+mt)*64 + lane holds lane's bf16x8 for a[mt][ks].
__global__ __launch_bounds__(128) void gen_h_kernel(
    const float* __restrict__ x, const float* __restrict__ w1,
    const float* __restrict__ b1, __hip_bfloat16* __restrict__ hswz)
{
    const int nb = blockIdx.x;
    const int n  = nb >> 6;
    const int b  = nb & 63;
    const int t  = threadIdx.x;

    __shared__ float xs[IN_DIM];
    #pragma unroll
    for (int i = 0; i < IN_DIM / 128; ++i)
        xs[t + i * 128] = x[b * IN_DIM + t + i * 128];
    __syncthreads();

    const float* w = w1 + (size_t)n * IN_DIM * HID + t;
    float a0 = 0.f, a1 = 0.f, a2 = 0.f, a3 = 0.f;
    #pragma unroll 4
    for (int i = 0; i < IN_DIM; i += 4) {
        a0 = fmaf(xs[i + 0], w[(size_t)(i + 0) * HID], a0);
        a1 = fmaf(xs[i + 1], w[(size_t)(i + 1) * HID], a1);
        a2 = fmaf(xs[i + 2], w[(size_t)(i + 2) * HID], a2);
        a3 = fmaf(xs[i + 3], w[(size_t)(i + 3) * HID], a3);
    }
    float acc = (a0 + a1) + (a2 + a3) + b1[n * HID + t];
    acc = fmaxf(acc, 0.f);

    const int mt = b >> 4, lr = b & 15;
    const int ks = t >> 5, lg = (t >> 3) & 3, ii = t & 7;
    const size_t idx = (size_t)n * 8192
                     + (size_t)(((ks * 4 + mt) * 64) + lg * 16 + lr) * 8 + ii;
    hswz[idx] = __float2bfloat16(acc);
}

// ---------------- Kernel B ----------------
// out[n][b][o] = h[n][b][:] . w2[n][:][o] + b2[n][o]
// Main loop: R8 structure, but A-fragments loaded per-chunk inside the loop
// (L2-hot) to cut VGPR below 128 -> 4 waves/SIMD (2 blocks/CU co-resident).
// vmcnt per iter: issue a(ks) x4 + stage(ks+1) x8 -> vmcnt(8) drains both
// stage(ks) and a(ks), leaves stage(ks+1) in flight.
__global__ __launch_bounds__(256, 4) void gen_out_mfma(
    const __hip_bfloat16* __restrict__ hswz, const float* __restrict__ w2,
    const float* __restrict__ b2, float* __restrict__ out)
{
    const int n    = blockIdx.y;
    const int tid  = threadIdx.x;
    const int wave = tid >> 6;
    const int lane = tid & 63;
    const int lr   = lane & 15;
    const int lg   = lane >> 4;
    const long oblk = (long)blockIdx.x * OTILE;
    const long wcol = oblk + wave * 64;          // wave's column base

    __shared__ float lds[2][4][32][64];          // 64 KB; [buf][wave][row][col]

    const float* w2n = w2 + (size_t)n * HID * ODIM;

    // stage chunk ks (rows ks*32..+31, wave's 64 cols) into lds[buf][wave].
    // source col pre-swizzled (G21 both-sides) by ((row>>3)&3)<<3.
    auto stage = [&](int buf, int ks) {
        #pragma unroll
        for (int p = 0; p < 8; ++p) {
            const int r   = 4 * p + lg;
            const int swz = ((r >> 3) & 3) << 3;
            const long col = wcol + ((lr * 4) ^ swz);
            long c = col > (long)ODIM - 4 ? (long)ODIM - 4 : col;
            gload_lds16(w2n + (size_t)(ks * 32 + r) * ODIM + c,
                        &lds[buf][wave][4 * p][0]);
        }
    };

    stage(0, 0);                                 // chunk 0 in flight ASAP

    const bf16x8* ha = (const bf16x8*)hswz + (size_t)n * 1024 + lane;

    // ---- bias scalars: b2 value for this lane's column in each tt-subtile
    float bias_s[4];
    #pragma unroll
    for (int tt = 0; tt < 4; ++tt) {
        long c = wcol + tt * 16 + lr;
        if (c > (long)ODIM - 1) c = (long)ODIM - 1;
        bias_s[tt] = b2[(size_t)n * ODIM + c];
    }

    f32x4 acc[4][4];
    #pragma unroll
    for (int tt = 0; tt < 4; ++tt)
        #pragma unroll
        for (int mt = 0; mt < 4; ++mt)
            acc[tt][mt] = f32x4{0.f, 0.f, 0.f, 0.f};

    #pragma unroll
    for (int ks = 0; ks < 4; ++ks) {
        // A fragments for this chunk (L1/L2-hot, coalesced 1KB loads)
        bf16x8 a[4];
        #pragma unroll
        for (int mt = 0; mt < 4; ++mt)
            a[mt] = ha[(ks * 4 + mt) * 64];

        if (ks < 3) {
            stage((ks + 1) & 1, ks + 1);         // next chunk stays in flight
            asm volatile("s_waitcnt vmcnt(8)" ::: "memory");   // chunk ks + a[] landed
        } else {
            asm volatile("s_waitcnt vmcnt(0)" ::: "memory");
        }
        __builtin_amdgcn_sched_barrier(0);       // don't hoist ds_read above wait

        const int buf = ks & 1;
        #pragma unroll
        for (int tt = 0; tt < 4; ++tt) {
            const int csw = (tt * 16 + lr) ^ (lg << 3);   // row>>3 == lg for rows lg*8+i
            const float* lp = &lds[buf][wave][lg * 8][csw];
            float bv[8];
            #pragma unroll
            for (int i = 0; i < 8; ++i)
                bv[i] = lp[(size_t)i * 64];
            bf16x8 bf;
            #pragma unroll
            for (int i = 0; i < 8; ++i)
                bf[i] = f2bf_bits(bv[i]);
            #pragma unroll
            for (int mt = 0; mt < 4; ++mt)
                acc[tt][mt] = __builtin_amdgcn_mfma_f32_16x16x32_bf16(
                                  a[mt], bf, acc[tt][mt], 0, 0, 0);
        }
        __builtin_amdgcn_sched_barrier(0);       // pin next stage below these ds_reads
    }

    // ---- cooperative epilogue: block transpose -> full-row 1KB stores.
    __syncthreads();                             // all waves done reading w2 LDS
    float* trs = &lds[0][0][0][0];               // view as [64][256]

    #pragma unroll
    for (int tt = 0; tt < 4; ++tt)
        #pragma unroll
        for (int mt = 0; mt < 4; ++mt)
            #pragma unroll
            for (int r = 0; r < 4; ++r)
                trs[(mt * 16 + lg * 4 + r) * 256 +
                    ((wave * 64 + tt * 16 + lr) ^ (lg << 3))] =
                    acc[tt][mt][r] + bias_s[tt];

    __syncthreads();

    const long gc = oblk + lane * 4;
    const bool ok = gc <= (long)ODIM - 4;
    #pragma unroll
    for (int j = 0; j < 16; ++j) {
        const int R  = wave * 16 + j;
        const int cR = ((j >> 2) & 3) << 3;      // == ((R>>2)&3)<<3
        f32x4 v = *(const f32x4*)&trs[R * 256 + ((lane * 4) ^ cR)];
        if (ok)
            __builtin_nontemporal_store(
                v, (f32x4*)(out + ((size_t)n * BATCH + R) * ODIM + gc));
    }
}

extern "C" void kernel_launch(void* const* d_in, const int* in_sizes, int n_in,
                              void* d_out, int out_size, void* d_ws, size_t ws_size,
                              hipStream_t stream)
{
    const float* x  = (const float*)d_in[0];
    const float* w1 = (const float*)d_in[1];
    const float* b1 = (const float*)d_in[2];
    const float* w2 = (const float*)d_in[3];
    const float* b2 = (const float*)d_in[4];
    float* out = (float*)d_out;
    __hip_bfloat16* hbf = (__hip_bfloat16*)d_ws;   // 384 KB swizzled h

    gen_h_kernel<<<dim3(N_DEC * BATCH), dim3(128), 0, stream>>>(x, w1, b1, hbf);

    gen_out_mfma<<<dim3(NXBLK, N_DEC), dim3(256), 0, stream>>>(hbf, w2, b2, out);
}